// Round 6
// baseline (140.171 us; speedup 1.0000x reference)
//
#include <hip/hip_runtime.h>
#include <math.h>

#define P 7
#define SCALE 0.125f
#define BB 4
#define CC 256
#define HH 128
#define WW 128
#define KK 512
#define NBIN 49
#define GPB 13            // bin-groups per ROI (4 bins each, 13*4 >= 49)
#define NXCD 8

__device__ __forceinline__ unsigned short f32_to_bf16_rne(float f) {
    unsigned int u = __float_as_uint(f);
    u += 0x7FFFu + ((u >> 16) & 1u);
    return (unsigned short)(u >> 16);
}

// Order-preserving bf16 -> u16 key. key(x) < key(y) <=> x < y (no NaN/Inf in data).
// key 0 is reserved: only bf16 0xFFFF (NaN) maps there, so 0 = "empty/masked".
__device__ __forceinline__ unsigned short bf16_key(unsigned short b) {
    return (b & 0x8000u) ? (unsigned short)(~b) : (unsigned short)(b | 0x8000u);
}

__device__ __forceinline__ unsigned int pkmax_u16(unsigned int a, unsigned int b) {
    unsigned int d;
    asm("v_pk_max_u16 %0, %1, %2" : "=v"(d) : "v"(a), "v"(b));
    return d;
}

// ---- Transpose+convert: [B,C,H,W] f32 -> [B,H*W,C] packed u16 keys ----
__global__ __launch_bounds__(1024) void transpose_cvt(
    const float* __restrict__ in, unsigned short* __restrict__ out)
{
    __shared__ float tile[64][65];    // tile[channel][pixel]
    const int p0 = blockIdx.x * 64;   // flat pixel tile
    const int c0 = blockIdx.y * 64;   // channel tile
    const int b  = blockIdx.z;
    const int tx = threadIdx.x;       // 0..63
    const int ty = threadIdx.y;       // 0..15

    const float* src = in + (size_t)b * CC * (HH * WW);
#pragma unroll
    for (int j = 0; j < 64; j += 16)
        tile[ty + j][tx] =
            __builtin_nontemporal_load(&src[(size_t)(c0 + ty + j) * (HH * WW) + p0 + tx]);
    __syncthreads();

    unsigned int* dst = (unsigned int*)(out + (size_t)b * (HH * WW) * CC);
    const int t = ty * 64 + tx;       // 0..1023
#pragma unroll
    for (int i = 0; i < 2; ++i) {
        const int flat = i * 1024 + t;    // 0..2047 (64 px * 32 uints)
        const int px = flat >> 5;
        const int cp = flat & 31;
        const unsigned int lo = bf16_key(f32_to_bf16_rne(tile[cp * 2][px]));
        const unsigned int hi = bf16_key(f32_to_bf16_rne(tile[cp * 2 + 1][px]));
        dst[((size_t)(p0 + px) * CC + c0) / 2 + cp] = lo | (hi << 16);
    }
}

// ---- Pool: one wave per bin, packed-u16 max, 2 pixels/wave-iter ----
__global__ __launch_bounds__(256) void pool_key(
    const unsigned short* __restrict__ fT,  // [B,HW,C] u16 keys
    const float* __restrict__ rois,         // [K,5]
    const float* __restrict__ masks,        // [K,H,W]
    float* __restrict__ out)                // [K,C,P,P]
{
    // XCD-aware swizzle: all GPB blocks of ROI k land on XCD k%8
    const int pid = blockIdx.x;             // 0 .. KK*GPB-1
    const int x   = pid & (NXCD - 1);
    const int t   = pid >> 3;
    const int g   = t % GPB;
    const int q   = t / GPB;
    const int k   = q * NXCD + x;

    const int wv   = threadIdx.x >> 6;
    const int lane = threadIdx.x & 63;
    const int bi   = g * 4 + wv;
    if (bi >= NBIN) return;                 // wave-uniform
    const int ph = bi / P;
    const int pw = bi % P;

    const int half = lane >> 5;             // which of 2 pixels per iter
    const int c8   = (lane & 31) * 8;       // 8 contiguous channels

    const float* roi = rois + k * 5;
    const int b  = (int)roi[0];
    const int sw = (int)rintf(roi[1] * SCALE);
    const int sh = (int)rintf(roi[2] * SCALE);
    const int ew = (int)rintf(roi[3] * SCALE);
    const int eh = (int)rintf(roi[4] * SCALE);
    const int roi_w = max(ew - sw + 1, 1);
    const int roi_h = max(eh - sh + 1, 1);

    const int hs = min(max((ph * roi_h) / P + sh, 0), HH);
    const int he = min(max(((ph + 1) * roi_h + P - 1) / P + sh, 0), HH);
    const int wl = min(max((pw * roi_w) / P + sw, 0), WW);
    const int wr = min(max(((pw + 1) * roi_w + P - 1) / P + sw, 0), WW);

    const unsigned int* fb =
        (const unsigned int*)(fT + (size_t)b * (HH * WW) * CC + c8);
    const float* m = masks + (size_t)k * (HH * WW);

    unsigned int a0 = 0, a1 = 0, a2 = 0, a3 = 0;   // packed key accumulators

    for (int w = wl; w < wr; w += 2) {
        const int wp = w + half;
        const bool valid = wp < wr;                 // half-uniform
        const int wc = min(wp, WW - 1);
        const unsigned int* fcol = fb + (size_t)wc * (CC / 2);
        const float* mcol = m + wc;
#pragma unroll 2
        for (int h = hs; h < he; ++h) {
            const float mv = mcol[h * WW];
            const uint4 kv = *(const uint4*)(fcol + (size_t)h * (WW * CC / 2));
            const bool on = valid && (mv > 0.5f);
            a0 = pkmax_u16(a0, on ? kv.x : 0u);
            a1 = pkmax_u16(a1, on ? kv.y : 0u);
            a2 = pkmax_u16(a2, on ? kv.z : 0u);
            a3 = pkmax_u16(a3, on ? kv.w : 0u);
        }
    }

    // combine pixel-halves (lane i <-> i+32 hold same channels)
    a0 = pkmax_u16(a0, (unsigned int)__shfl_xor((int)a0, 32, 64));
    a1 = pkmax_u16(a1, (unsigned int)__shfl_xor((int)a1, 32, 64));
    a2 = pkmax_u16(a2, (unsigned int)__shfl_xor((int)a2, 32, 64));
    a3 = pkmax_u16(a3, (unsigned int)__shfl_xor((int)a3, 32, 64));

    if (half == 0) {
        const unsigned int acc[4] = {a0, a1, a2, a3};
        float* o = out + ((size_t)k * CC + c8) * NBIN + ph * P + pw;
#pragma unroll
        for (int j = 0; j < 8; ++j) {
            const unsigned int d = acc[j >> 1];
            const unsigned int key = (j & 1) ? (d >> 16) : (d & 0xFFFFu);
            float r;
            if (key == 0u) {
                r = 0.0f;                       // empty / fully-masked bin
            } else {
                const unsigned int bbits =
                    (key & 0x8000u) ? (key ^ 0x8000u) : (~key & 0xFFFFu);
                r = __uint_as_float(bbits << 16);
            }
            o[(size_t)j * NBIN] = r;
        }
    }
}

// ---------- Fallback (NCHW direct, correctness-only path) ----------
__global__ __launch_bounds__(256) void ROIPool_nchw_kernel(
    const float* __restrict__ inputs, const float* __restrict__ rois,
    const float* __restrict__ masks, float* __restrict__ out)
{
    const int k  = blockIdx.x;
    const int ph = blockIdx.y;
    const int c  = threadIdx.x;

    const float* roi = rois + k * 5;
    const int b  = (int)roi[0];
    const int sw = (int)rintf(roi[1] * SCALE);
    const int sh = (int)rintf(roi[2] * SCALE);
    const int ew = (int)rintf(roi[3] * SCALE);
    const int eh = (int)rintf(roi[4] * SCALE);
    const int roi_w = max(ew - sw + 1, 1);
    const int roi_h = max(eh - sh + 1, 1);

    const int hs = min(max((ph * roi_h) / P + sh, 0), HH);
    const int he = min(max(((ph + 1) * roi_h + P - 1) / P + sh, 0), HH);

    int wsb[P], web[P];
#pragma unroll
    for (int pw = 0; pw < P; ++pw) {
        wsb[pw] = min(max((pw * roi_w) / P + sw, 0), WW);
        web[pw] = min(max(((pw + 1) * roi_w + P - 1) / P + sw, 0), WW);
    }

    const float* f = inputs + ((size_t)b * CC + c) * (HH * WW);
    const float* m = masks  + (size_t)k * (HH * WW);

    float vmax[P];
#pragma unroll
    for (int pw = 0; pw < P; ++pw) vmax[pw] = -INFINITY;

    for (int h = hs; h < he; ++h) {
        const float* frow = f + h * WW;
        const float* mrow = m + h * WW;
#pragma unroll
        for (int pw = 0; pw < P; ++pw) {
            float v = vmax[pw];
            for (int w = wsb[pw]; w < web[pw]; ++w)
                if (mrow[w] > 0.5f) v = fmaxf(v, frow[w]);
            vmax[pw] = v;
        }
    }

    float* o = out + (((size_t)k * CC + c) * P + ph) * P;
#pragma unroll
    for (int pw = 0; pw < P; ++pw) {
        const float v = vmax[pw];
        o[pw] = isinf(v) ? 0.0f : v;
    }
}

extern "C" void kernel_launch(void* const* d_in, const int* in_sizes, int n_in,
                              void* d_out, int out_size, void* d_ws, size_t ws_size,
                              hipStream_t stream) {
    const float* inputs = (const float*)d_in[0];
    const float* rois   = (const float*)d_in[1];
    const float* masks  = (const float*)d_in[2];
    float* out = (float*)d_out;

    const size_t need = (size_t)BB * CC * HH * WW * sizeof(unsigned short); // 32 MiB

    if (ws_size >= need) {
        unsigned short* fT = (unsigned short*)d_ws;
        {
            dim3 grid((HH * WW) / 64, CC / 64, BB);
            dim3 block(64, 16);
            transpose_cvt<<<grid, block, 0, stream>>>(inputs, fT);
        }
        {
            dim3 grid(KK * GPB);
            dim3 block(256);
            pool_key<<<grid, block, 0, stream>>>(fT, rois, masks, out);
        }
    } else {
        dim3 grid(KK, P);
        dim3 block(CC);
        ROIPool_nchw_kernel<<<grid, block, 0, stream>>>(inputs, rois, masks, out);
    }
}

// Round 7
// 120.321 us; speedup vs baseline: 1.1650x; 1.1650x over previous
//
#include <hip/hip_runtime.h>
#include <math.h>

#define P 7
#define SCALE 0.125f
#define BB 4
#define CC 256
#define HH 128
#define WW 128
#define KK 512
#define NBIN 49
#define GPB 13            // bin-groups per ROI (4 bins each, 13*4 >= 49)
#define NXCD 8

__device__ __forceinline__ unsigned short f32_to_bf16_rne(float f) {
    unsigned int u = __float_as_uint(f);
    u += 0x7FFFu + ((u >> 16) & 1u);
    return (unsigned short)(u >> 16);
}

// Order-preserving bf16 -> u16 key. key(x) < key(y) <=> x < y (no NaN/Inf in data).
// key 0 is reserved: only bf16 0xFFFF (NaN) maps there, so 0 = "empty/masked".
__device__ __forceinline__ unsigned short bf16_key(unsigned short b) {
    return (b & 0x8000u) ? (unsigned short)(~b) : (unsigned short)(b | 0x8000u);
}

__device__ __forceinline__ unsigned int pkmax_u16(unsigned int a, unsigned int b) {
    unsigned int d;
    asm("v_pk_max_u16 %0, %1, %2" : "=v"(d) : "v"(a), "v"(b));
    return d;
}

// ---- Transpose+convert: [B,C,H,W] f32 -> [B,H*W,C] packed u16 keys ----
__global__ __launch_bounds__(1024) void transpose_cvt(
    const float* __restrict__ in, unsigned short* __restrict__ out)
{
    __shared__ float tile[64][65];    // tile[channel][pixel]
    const int p0 = blockIdx.x * 64;   // flat pixel tile
    const int c0 = blockIdx.y * 64;   // channel tile
    const int b  = blockIdx.z;
    const int tx = threadIdx.x;       // 0..63
    const int ty = threadIdx.y;       // 0..15

    const float* src = in + (size_t)b * CC * (HH * WW);
#pragma unroll
    for (int j = 0; j < 64; j += 16)
        tile[ty + j][tx] =
            __builtin_nontemporal_load(&src[(size_t)(c0 + ty + j) * (HH * WW) + p0 + tx]);
    __syncthreads();

    unsigned int* dst = (unsigned int*)(out + (size_t)b * (HH * WW) * CC);
    const int t = ty * 64 + tx;       // 0..1023
#pragma unroll
    for (int i = 0; i < 2; ++i) {
        const int flat = i * 1024 + t;    // 0..2047 (64 px * 32 uints)
        const int px = flat >> 5;
        const int cp = flat & 31;
        const unsigned int lo = bf16_key(f32_to_bf16_rne(tile[cp * 2][px]));
        const unsigned int hi = bf16_key(f32_to_bf16_rne(tile[cp * 2 + 1][px]));
        dst[((size_t)(p0 + px) * CC + c0) / 2 + cp] = lo | (hi << 16);
    }
}

// ---- Pool: one wave per bin, 8-pixel chunks, 4 loads in flight ----
__global__ __launch_bounds__(256) void pool_key(
    const unsigned short* __restrict__ fT,  // [B,HW,C] u16 keys
    const float* __restrict__ rois,         // [K,5]
    const float* __restrict__ masks,        // [K,H,W]
    float* __restrict__ out)                // [K,C,P,P]
{
    // XCD-aware swizzle: all GPB blocks of ROI k land on XCD k%8
    const int pid = blockIdx.x;             // 0 .. KK*GPB-1
    const int x   = pid & (NXCD - 1);
    const int t   = pid >> 3;
    const int g   = t % GPB;
    const int q   = t / GPB;
    const int k   = q * NXCD + x;

    const int wv   = threadIdx.x >> 6;
    const int lane = threadIdx.x & 63;
    const int bi   = g * 4 + wv;
    if (bi >= NBIN) return;                 // wave-uniform
    const int ph = bi / P;
    const int pw = bi % P;

    const int half = lane >> 5;             // even/odd pixel of each pair
    const int c4   = (lane & 31) * 4;       // uint offset: 8 channels

    const float* roi = rois + k * 5;
    const int b  = (int)roi[0];
    const int sw = (int)rintf(roi[1] * SCALE);
    const int sh = (int)rintf(roi[2] * SCALE);
    const int ew = (int)rintf(roi[3] * SCALE);
    const int eh = (int)rintf(roi[4] * SCALE);
    const int roi_w = max(ew - sw + 1, 1);
    const int roi_h = max(eh - sh + 1, 1);

    const int hs = min(max((ph * roi_h) / P + sh, 0), HH);
    const int he = min(max(((ph + 1) * roi_h + P - 1) / P + sh, 0), HH);
    const int wl = min(max((pw * roi_w) / P + sw, 0), WW);
    const int wr = min(max(((pw + 1) * roi_w + P - 1) / P + sw, 0), WW);

    const unsigned int* fb =
        (const unsigned int*)(fT + (size_t)b * (HH * WW) * CC) + c4;
    const float* m = masks + (size_t)k * (HH * WW);

    unsigned int a0 = 0, a1 = 0, a2 = 0, a3 = 0;   // packed key accumulators

    for (int h = hs; h < he; ++h) {
        const float* mrow = m + h * WW;
        const unsigned int* frow = fb + (size_t)h * WW * (CC / 2);
        for (int w0 = wl; w0 < wr; w0 += 8) {
            uint4 kv[4];
            float mv[4];
            bool  on[4];
#pragma unroll
            for (int p = 0; p < 4; ++p) {
                const int wp = w0 + p * 2 + half;
                const int wc = min(wp, wr - 1);
                mv[p] = mrow[wc];
                kv[p] = *(const uint4*)(frow + (size_t)wc * (CC / 2));
                on[p] = (wp < wr);
            }
#pragma unroll
            for (int p = 0; p < 4; ++p) {
                const bool use = on[p] && (mv[p] > 0.5f);
                a0 = pkmax_u16(a0, use ? kv[p].x : 0u);
                a1 = pkmax_u16(a1, use ? kv[p].y : 0u);
                a2 = pkmax_u16(a2, use ? kv[p].z : 0u);
                a3 = pkmax_u16(a3, use ? kv[p].w : 0u);
            }
        }
    }

    // combine pixel-halves (lane i <-> i+32 hold same channels)
    a0 = pkmax_u16(a0, (unsigned int)__shfl_xor((int)a0, 32, 64));
    a1 = pkmax_u16(a1, (unsigned int)__shfl_xor((int)a1, 32, 64));
    a2 = pkmax_u16(a2, (unsigned int)__shfl_xor((int)a2, 32, 64));
    a3 = pkmax_u16(a3, (unsigned int)__shfl_xor((int)a3, 32, 64));

    if (half == 0) {
        const unsigned int acc[4] = {a0, a1, a2, a3};
        float* o = out + ((size_t)k * CC + (size_t)c4 * 2) * NBIN + ph * P + pw;
#pragma unroll
        for (int j = 0; j < 8; ++j) {
            const unsigned int d = acc[j >> 1];
            const unsigned int key = (j & 1) ? (d >> 16) : (d & 0xFFFFu);
            float r;
            if (key == 0u) {
                r = 0.0f;                       // empty / fully-masked bin
            } else {
                const unsigned int bbits =
                    (key & 0x8000u) ? (key ^ 0x8000u) : (~key & 0xFFFFu);
                r = __uint_as_float(bbits << 16);
            }
            o[(size_t)j * NBIN] = r;
        }
    }
}

// ---------- Fallback (NCHW direct, correctness-only path) ----------
__global__ __launch_bounds__(256) void ROIPool_nchw_kernel(
    const float* __restrict__ inputs, const float* __restrict__ rois,
    const float* __restrict__ masks, float* __restrict__ out)
{
    const int k  = blockIdx.x;
    const int ph = blockIdx.y;
    const int c  = threadIdx.x;

    const float* roi = rois + k * 5;
    const int b  = (int)roi[0];
    const int sw = (int)rintf(roi[1] * SCALE);
    const int sh = (int)rintf(roi[2] * SCALE);
    const int ew = (int)rintf(roi[3] * SCALE);
    const int eh = (int)rintf(roi[4] * SCALE);
    const int roi_w = max(ew - sw + 1, 1);
    const int roi_h = max(eh - sh + 1, 1);

    const int hs = min(max((ph * roi_h) / P + sh, 0), HH);
    const int he = min(max(((ph + 1) * roi_h + P - 1) / P + sh, 0), HH);

    int wsb[P], web[P];
#pragma unroll
    for (int pw = 0; pw < P; ++pw) {
        wsb[pw] = min(max((pw * roi_w) / P + sw, 0), WW);
        web[pw] = min(max(((pw + 1) * roi_w + P - 1) / P + sw, 0), WW);
    }

    const float* f = inputs + ((size_t)b * CC + c) * (HH * WW);
    const float* m = masks  + (size_t)k * (HH * WW);

    float vmax[P];
#pragma unroll
    for (int pw = 0; pw < P; ++pw) vmax[pw] = -INFINITY;

    for (int h = hs; h < he; ++h) {
        const float* frow = f + h * WW;
        const float* mrow = m + h * WW;
#pragma unroll
        for (int pw = 0; pw < P; ++pw) {
            float v = vmax[pw];
            for (int w = wsb[pw]; w < web[pw]; ++w)
                if (mrow[w] > 0.5f) v = fmaxf(v, frow[w]);
            vmax[pw] = v;
        }
    }

    float* o = out + (((size_t)k * CC + c) * P + ph) * P;
#pragma unroll
    for (int pw = 0; pw < P; ++pw) {
        const float v = vmax[pw];
        o[pw] = isinf(v) ? 0.0f : v;
    }
}

extern "C" void kernel_launch(void* const* d_in, const int* in_sizes, int n_in,
                              void* d_out, int out_size, void* d_ws, size_t ws_size,
                              hipStream_t stream) {
    const float* inputs = (const float*)d_in[0];
    const float* rois   = (const float*)d_in[1];
    const float* masks  = (const float*)d_in[2];
    float* out = (float*)d_out;

    const size_t need = (size_t)BB * CC * HH * WW * sizeof(unsigned short); // 32 MiB

    if (ws_size >= need) {
        unsigned short* fT = (unsigned short*)d_ws;
        {
            dim3 grid((HH * WW) / 64, CC / 64, BB);
            dim3 block(64, 16);
            transpose_cvt<<<grid, block, 0, stream>>>(inputs, fT);
        }
        {
            dim3 grid(KK * GPB);
            dim3 block(256);
            pool_key<<<grid, block, 0, stream>>>(fT, rois, masks, out);
        }
    } else {
        dim3 grid(KK, P);
        dim3 block(CC);
        ROIPool_nchw_kernel<<<grid, block, 0, stream>>>(inputs, rois, masks, out);
    }
}